// Round 2
// baseline (133961.255 us; speedup 1.0000x reference)
//
#include <hip/hip_runtime.h>
#include <cstdint>
#include <cstddef>

#define BDIM 256
#define NWG  256

// problem dims
constexpr int B_ = 64, S_ = 1024, I_ = 128, H_ = 512, O_ = 128;
constexpr size_t HB = (size_t)H_ * B_;   // 32768 floats per h-slab ([k][b] layout)

// ---------------- workspace layout (float offsets), total ~11.3 MB ----------------
constexpr size_t N_W0 = 512 * 640;    // L0 gate weights transposed+concat [j][640] = [Wh ; Wx]
constexpr size_t N_W1 = 512 * 1024;   // L1 [j][1024] = [Wx ; Wh]
constexpr size_t RH0_OFF = 0;                       // [512][64]
constexpr size_t RH1_OFF = RH0_OFF + HB;
constexpr size_t Y1R_OFF = RH1_OFF + HB;            // ring: 2 slabs [512][64]
constexpr size_t Y2R_OFF = Y1R_OFF + 2 * HB;        // ring: 2 slabs
constexpr size_t WZ0_OFF = Y2R_OFF + 2 * HB;
constexpr size_t WR0_OFF = WZ0_OFF + N_W0;
constexpr size_t WG0_OFF = WR0_OFF + N_W0;
constexpr size_t WZ1_OFF = WG0_OFF + N_W0;
constexpr size_t WR1_OFF = WZ1_OFF + N_W1;
constexpr size_t WG1_OFF = WR1_OFF + N_W1;
constexpr size_t WOT_OFF = WG1_OFF + N_W1;          // WoutT [128][512]
constexpr size_t BAR_OFF = WOT_OFF + (size_t)O_ * H_;  // 64 uints
constexpr size_t WS_FLOATS = BAR_OFF + 64;          // 2,818,112 floats ~= 11.3 MB

// ---------------- init: transpose/concat weights, WoutT, seed ring slab 0, zero barrier ----------------
struct InitArgs {
  const float *Wzx0, *Wzh0, *Wrx0, *Wrh0, *Wgx0, *Wgh0;
  const float *Wzx1, *Wzh1, *Wrx1, *Wrh1, *Wgx1, *Wgh1;
  const float *Wout, *hidden;
  float* ws;
};

__global__ void k_init(InitArgs a) {
  const size_t NWOT = (size_t)O_ * H_;
  const size_t total = 3 * N_W0 + 3 * N_W1 + NWOT + 2 * HB + 64;
  for (size_t i = (size_t)blockIdx.x * blockDim.x + threadIdx.x; i < total;
       i += (size_t)gridDim.x * blockDim.x) {
    size_t r = i;
    if (r < N_W0) {  // Wz0 = [Wzh0 ; Wzx0]
      size_t j = r / 640, k = r % 640;
      a.ws[WZ0_OFF + r] = (k < 512) ? a.Wzh0[k * 512 + j] : a.Wzx0[(k - 512) * 512 + j];
      continue;
    }
    r -= N_W0;
    if (r < N_W0) {
      size_t j = r / 640, k = r % 640;
      a.ws[WR0_OFF + r] = (k < 512) ? a.Wrh0[k * 512 + j] : a.Wrx0[(k - 512) * 512 + j];
      continue;
    }
    r -= N_W0;
    if (r < N_W0) {
      size_t j = r / 640, k = r % 640;
      a.ws[WG0_OFF + r] = (k < 512) ? a.Wgh0[k * 512 + j] : a.Wgx0[(k - 512) * 512 + j];
      continue;
    }
    r -= N_W0;
    if (r < N_W1) {  // Wz1 = [Wzx1 ; Wzh1] (x first: matches S1-then-S3 chunk order)
      size_t j = r / 1024, k = r % 1024;
      a.ws[WZ1_OFF + r] = (k < 512) ? a.Wzx1[k * 512 + j] : a.Wzh1[(k - 512) * 512 + j];
      continue;
    }
    r -= N_W1;
    if (r < N_W1) {
      size_t j = r / 1024, k = r % 1024;
      a.ws[WR1_OFF + r] = (k < 512) ? a.Wrx1[k * 512 + j] : a.Wrh1[(k - 512) * 512 + j];
      continue;
    }
    r -= N_W1;
    if (r < N_W1) {
      size_t j = r / 1024, k = r % 1024;
      a.ws[WG1_OFF + r] = (k < 512) ? a.Wgx1[k * 512 + j] : a.Wgh1[(k - 512) * 512 + j];
      continue;
    }
    r -= N_W1;
    if (r < NWOT) {  // WoutT[o][k] = Wout[k][o]
      size_t o = r >> 9, k = r & 511;
      a.ws[WOT_OFF + r] = a.Wout[k * 128 + o];
      continue;
    }
    r -= NWOT;
    if (r < HB) {  // Y1 ring slab 0 (parity 0): h0 of layer 0
      size_t k = r >> 6, b = r & 63;
      a.ws[Y1R_OFF + r] = a.hidden[b * 1024 + k];
      continue;
    }
    r -= HB;
    if (r < HB) {  // Y2 ring slab 0: h0 of layer 1
      size_t k = r >> 6, b = r & 63;
      a.ws[Y2R_OFF + r] = a.hidden[b * 1024 + 512 + k];
      continue;
    }
    r -= HB;
    ((unsigned int*)(a.ws + BAR_OFF))[r] = 0u;
  }
}

// ---------------- scan helpers ----------------
// load rows [0,256) of a [K][64] slab; cols [bb,bb+16) transposed into hch[b][k]
__device__ __forceinline__ void load_chunk256(float hch[16][260], const float* __restrict__ src,
                                              int bb, int tid) {
  #pragma unroll
  for (int r = 0; r < 4; ++r) {
    int idx = tid + (r << 8);
    int kk = idx >> 2;
    int bq = (idx & 3) << 2;
    float4 v = *(const float4*)(src + ((size_t)kk << 6) + bb + bq);
    hch[bq + 0][kk] = v.x; hch[bq + 1][kk] = v.y;
    hch[bq + 2][kk] = v.z; hch[bq + 3][kk] = v.w;
  }
}

// load x[bb+row][t][0:128] into hch[row][0:128] straight from the original layout
__device__ __forceinline__ void load_x(float hch[16][260], const float* __restrict__ x,
                                       int t, int bb, int tid) {
  #pragma unroll
  for (int r = 0; r < 2; ++r) {
    int idx = tid + (r << 8);
    int row = idx >> 5;          // 0..15
    int c4  = idx & 31;          // 0..31
    float4 v = *(const float4*)(x + ((size_t)(bb + row) * 1024 + t) * 128 + (c4 << 2));
    *(float4*)&hch[row][c4 << 2] = v;
  }
}

__device__ __forceinline__ void fma4(float4& a, const float4 h, const float4 w) {
  a.x = fmaf(h.x, w.x, a.x); a.y = fmaf(h.y, w.y, a.y);
  a.z = fmaf(h.z, w.z, a.z); a.w = fmaf(h.w, w.w, a.w);
}

__device__ __forceinline__ void dot_n(const float* hrow, const float* __restrict__ w, int len,
                                      float4& a) {
  #pragma unroll 8
  for (int k = 0; k < len; k += 4) {
    float4 h4 = *(const float4*)(hrow + k);
    float4 wv = *(const float4*)(w + k);
    fma4(a, h4, wv);
  }
}

__device__ __forceinline__ void dot2_256(const float* hrow, const float* __restrict__ w0,
                                         const float* __restrict__ w1, float4& a0, float4& a1) {
  #pragma unroll 4
  for (int k = 0; k < 256; k += 4) {
    float4 h4 = *(const float4*)(hrow + k);
    float4 v0 = *(const float4*)(w0 + k);
    float4 v1 = *(const float4*)(w1 + k);
    fma4(a0, h4, v0);
    fma4(a1, h4, v1);
  }
}

__device__ __forceinline__ void grid_barrier(unsigned int* cnt, unsigned int* gen) {
  __threadfence();     // drain this wave's global writes (agent scope)
  __syncthreads();
  if (threadIdx.x == 0) {
    unsigned int g = __hip_atomic_load(gen, __ATOMIC_RELAXED, __HIP_MEMORY_SCOPE_AGENT);
    unsigned int arr = __hip_atomic_fetch_add(cnt, 1u, __ATOMIC_ACQ_REL, __HIP_MEMORY_SCOPE_AGENT);
    if (arr == NWG - 1) {
      __hip_atomic_store(cnt, 0u, __ATOMIC_RELAXED, __HIP_MEMORY_SCOPE_AGENT);
      __hip_atomic_store(gen, g + 1u, __ATOMIC_RELEASE, __HIP_MEMORY_SCOPE_AGENT);
    } else {
      while (__hip_atomic_load(gen, __ATOMIC_RELAXED, __HIP_MEMORY_SCOPE_AGENT) == g) {
        __builtin_amdgcn_s_sleep(2);
      }
    }
  }
  __syncthreads();
  __threadfence();
}

// ---------------- the persistent scan (plain launch; 256 WGs x 4 waves is trivially co-resident
// on 256 CUs / 8192-wave capacity for a solo kernel) ----------------
struct ScanArgs {
  float* ws;
  const float* xin;
  float* out;
  const float *bz0, *br0, *bg0, *bz1, *br1, *bg1, *bout;
};

__launch_bounds__(BDIM, 1)
__global__ void k_scan(ScanArgs a) {
  float* ws = a.ws;
  float* rh0 = ws + RH0_OFF;
  float* rh1 = ws + RH1_OFF;
  float* Y1r = ws + Y1R_OFF;
  float* Y2r = ws + Y2R_OFF;
  const float* Wz0 = ws + WZ0_OFF;
  const float* Wr0 = ws + WR0_OFF;
  const float* Wg0 = ws + WG0_OFF;
  const float* Wz1 = ws + WZ1_OFF;
  const float* Wr1 = ws + WR1_OFF;
  const float* Wg1 = ws + WG1_OFF;
  const float* WoT = ws + WOT_OFF;
  unsigned int* bar = (unsigned int*)(ws + BAR_OFF);
  unsigned int* cnt = bar;
  unsigned int* gen = bar + 32;

  const int tid = threadIdx.x;
  const int wg  = blockIdx.x;
  const int bb  = (wg & 3) << 4;   // batch block [bb, bb+16)
  const int j0  = (wg >> 2) << 3;  // h-column block [j0, j0+8)

  // stage A mapping: (jg 0..15) x (b 0..15); jg -> (gate, col)
  const int aB  = tid & 15;
  const int ajg = tid >> 4;
  const int aG  = ajg & 1;        // 0: z, 1: r
  const int aJ  = j0 + (ajg >> 1);
  const int aJJ = ajg >> 1;
  // stage B mapping: (rest 0..15) x (b 0..15); rest -> (layer, col), layer on wave boundary
  const int bB   = tid & 15;
  const int rest = tid >> 4;
  const int bL   = rest >> 3;     // waves 0-1: layer0, waves 2-3: layer1
  const int bJJ  = rest & 7;
  const int bJ   = j0 + bJJ;
  // phase O mapping: (ojg 0..15) x (b 0..15); ojg -> (col-of-2, k8)
  const int oB   = tid & 15;
  const int ojg  = tid >> 4;
  const int oCol = ojg & 1;
  const int oK8  = ojg >> 1;      // 0..7, 64-wide k slice
  const int ocBase = (wg >> 2) << 1;   // out cols [ocBase, ocBase+2)

  __shared__ float hch[16][260];
  __shared__ float zb[2][8][16];
  __shared__ float hpb[2][8][16];
  __shared__ float pb[16][17];

  const float* WA0 = (aG ? Wr0 : Wz0) + (size_t)aJ * 640;
  const float* WA1 = (aG ? Wr1 : Wz1) + (size_t)aJ * 1024;
  const float biasA0 = (aG ? a.br0 : a.bz0)[aJ];
  const float biasA1 = (aG ? a.br1 : a.bz1)[aJ];
  const float* WB = bL ? (Wg1 + (size_t)bJ * 1024) : (Wg0 + (size_t)bJ * 640);
  const float biasB = (bL ? a.bg1 : a.bg0)[bJ];
  const float* WOrow = WoT + (size_t)(ocBase + oCol) * 512 + (oK8 << 6);

  // stage tau: L0 step tau (tau<1024), L1 step tau-1 (1<=tau<=1024), outproj t=tau-2 (tau>=2)
  for (int tau = 0; tau <= S_ + 1; ++tau) {
    const bool doL0 = (tau < S_);
    const bool doL1 = (tau >= 1) && (tau <= S_);
    const bool doOut = (tau >= 2);
    const float* S1 = Y1r + (size_t)(tau & 1) * HB;          // L0 h_prev AND L1 x (slab tau)
    const float* S3 = Y2r + (size_t)((tau - 1) & 1) * HB;    // L1 h_prev (slab tau-1)

    // -------- phase O: out[:, tau-2, :] from Y2 slab tau-1 (visible since last barrier) ----
    if (doOut) {
      float p = 0.f;
      #pragma unroll 1
      for (int c = 0; c < 2; ++c) {
        __syncthreads();
        load_chunk256(hch, S3 + (size_t)c * 16384, bb, tid);
        __syncthreads();
        if ((oK8 >> 2) == c) {
          float4 acc = {0.f, 0.f, 0.f, 0.f};
          dot_n(&hch[oB][(oK8 & 3) << 6], WOrow, 64, acc);
          p = acc.x + acc.y + acc.z + acc.w;
        }
      }
      pb[ojg][oB] = p;
      __syncthreads();
      if (ojg < 2) {
        float s = a.bout[ocBase + ojg];
        #pragma unroll
        for (int q = 0; q < 8; ++q) s += pb[(q << 1) | ojg][oB];
        a.out[((size_t)(bb + oB) * 1024 + (tau - 2)) * 128 + ocBase + ojg] = s;
      }
    }

    // -------- stage A: z, r for both layers --------
    float4 acc0 = {0.f, 0.f, 0.f, 0.f}, acc1 = {0.f, 0.f, 0.f, 0.f};
    float hp0 = 0.f, hp1 = 0.f;

    if (doL0 || doL1) {
      #pragma unroll 1
      for (int c = 0; c < 2; ++c) {  // S1: k in [0,512)
        __syncthreads();
        load_chunk256(hch, S1 + (size_t)c * 16384, bb, tid);
        __syncthreads();
        const float* hrow = &hch[aB][0];
        if (doL0 && doL1)      dot2_256(hrow, WA0 + (c << 8), WA1 + (c << 8), acc0, acc1);
        else if (doL0)         dot_n(hrow, WA0 + (c << 8), 256, acc0);
        else                   dot_n(hrow, WA1 + (c << 8), 256, acc1);
        int d = aJ - (c << 8);
        if (aG && d >= 0 && d < 256) hp0 = hch[aB][d];   // L0 h_prev[b][aJ]
      }
    }
    if (doL0) {  // x chunk: L0 x-part, W rows [512,640)
      __syncthreads();
      load_x(hch, a.xin, tau, bb, tid);
      __syncthreads();
      dot_n(&hch[aB][0], WA0 + 512, 128, acc0);
    }
    if (doL1) {  // S3: L1 h-part, W rows [512,1024)
      #pragma unroll 1
      for (int c = 0; c < 2; ++c) {
        __syncthreads();
        load_chunk256(hch, S3 + (size_t)c * 16384, bb, tid);
        __syncthreads();
        dot_n(&hch[aB][0], WA1 + 512 + (c << 8), 256, acc1);
        int d = aJ - (c << 8);
        if (aG && d >= 0 && d < 256) hp1 = hch[aB][d];   // L1 h_prev[b][aJ]
      }
    }
    if (doL0) {
      float s = acc0.x + acc0.y + acc0.z + acc0.w + biasA0;
      float v = 1.0f / (1.0f + __expf(-s));
      if (aG == 0) zb[0][aJJ][aB] = v;
      else { hpb[0][aJJ][aB] = hp0; rh0[(size_t)aJ * 64 + bb + aB] = v * hp0; }
    }
    if (doL1) {
      float s = acc1.x + acc1.y + acc1.z + acc1.w + biasA1;
      float v = 1.0f / (1.0f + __expf(-s));
      if (aG == 0) zb[1][aJJ][aB] = v;
      else { hpb[1][aJJ][aB] = hp1; rh1[(size_t)aJ * 64 + bb + aB] = v * hp1; }
    }

    grid_barrier(cnt, gen);   // rh visible grid-wide

    // -------- stage B: g and h update --------
    float4 accB = {0.f, 0.f, 0.f, 0.f};
    if (doL0) {
      #pragma unroll 1
      for (int c = 0; c < 2; ++c) {  // rh0: W rows [0,512)
        __syncthreads();
        load_chunk256(hch, rh0 + (size_t)c * 16384, bb, tid);
        __syncthreads();
        if (bL == 0) dot_n(&hch[bB][0], WB + (c << 8), 256, accB);
      }
      __syncthreads();               // x: W rows [512,640)
      load_x(hch, a.xin, tau, bb, tid);
      __syncthreads();
      if (bL == 0) dot_n(&hch[bB][0], WB + 512, 128, accB);
    }
    if (doL1) {
      #pragma unroll 1
      for (int c = 0; c < 2; ++c) {  // Y1[tau] (L1 x): W rows [0,512)
        __syncthreads();
        load_chunk256(hch, S1 + (size_t)c * 16384, bb, tid);
        __syncthreads();
        if (bL == 1) dot_n(&hch[bB][0], WB + (c << 8), 256, accB);
      }
      #pragma unroll 1
      for (int c = 0; c < 2; ++c) {  // rh1: W rows [512,1024)
        __syncthreads();
        load_chunk256(hch, rh1 + (size_t)c * 16384, bb, tid);
        __syncthreads();
        if (bL == 1) dot_n(&hch[bB][0], WB + 512 + (c << 8), 256, accB);
      }
    }
    const bool act = bL ? doL1 : doL0;
    if (act) {
      float s = accB.x + accB.y + accB.z + accB.w + biasB;
      float gg = tanhf(s);
      float z  = zb[bL][bJJ][bB];
      float hp = hpb[bL][bJJ][bB];
      float hn = fmaf(z, hp - gg, gg);  // z*hp + (1-z)*g
      if (bL == 0) Y1r[(size_t)((tau + 1) & 1) * HB + (size_t)bJ * 64 + bb + bB] = hn;
      else         Y2r[(size_t)(tau & 1) * HB + (size_t)bJ * 64 + bb + bB] = hn;
    }

    grid_barrier(cnt, gen);   // ring slabs visible for next stage
  }
}

// ---------------- final hidden states: out[BSO + b*1024 + l*512 + j] ----------------
// L0 final = Y1 slab 1024 (parity 0); L1 final = Y2 slab 1024 (parity 0)
__global__ void k_hidden(const float* __restrict__ ws, float* __restrict__ out) {
  int idx = blockIdx.x * 256 + threadIdx.x;   // 65536 total
  int b = idx >> 10, rem = idx & 1023, l = rem >> 9, j = rem & 511;
  const float* src = ws + (l ? Y2R_OFF : Y1R_OFF) + (size_t)j * 64 + b;
  out[(size_t)B_ * S_ * O_ + idx] = *src;
}

// ---------------- launch ----------------
extern "C" void kernel_launch(void* const* d_in, const int* in_sizes, int n_in,
                              void* d_out, int out_size, void* d_ws, size_t ws_size,
                              hipStream_t stream) {
  const float* input  = (const float*)d_in[0];
  const float* hidden = (const float*)d_in[1];
  const float* Wzx0 = (const float*)d_in[2],  *Wzh0 = (const float*)d_in[3],  *bz0 = (const float*)d_in[4];
  const float* Wrx0 = (const float*)d_in[5],  *Wrh0 = (const float*)d_in[6],  *br0 = (const float*)d_in[7];
  const float* Wgx0 = (const float*)d_in[8],  *Wgh0 = (const float*)d_in[9],  *bg0 = (const float*)d_in[10];
  const float* Wzx1 = (const float*)d_in[11], *Wzh1 = (const float*)d_in[12], *bz1 = (const float*)d_in[13];
  const float* Wrx1 = (const float*)d_in[14], *Wrh1 = (const float*)d_in[15], *br1 = (const float*)d_in[16];
  const float* Wgx1 = (const float*)d_in[17], *Wgh1 = (const float*)d_in[18], *bg1 = (const float*)d_in[19];
  const float* Wout = (const float*)d_in[20], *bout = (const float*)d_in[21];
  float* ws = (float*)d_ws;
  float* out = (float*)d_out;

  InitArgs ia{Wzx0, Wzh0, Wrx0, Wrh0, Wgx0, Wgh0,
              Wzx1, Wzh1, Wrx1, Wrh1, Wgx1, Wgh1, Wout, hidden, ws};
  k_init<<<2048, BDIM, 0, stream>>>(ia);

  ScanArgs sa{ws, input, out, bz0, br0, bg0, bz1, br1, bg1, bout};
  k_scan<<<dim3(NWG), dim3(BDIM), 0, stream>>>(sa);

  k_hidden<<<256, 256, 0, stream>>>(ws, out);
}

// Round 3
// 101091.156 us; speedup vs baseline: 1.3252x; 1.3252x over previous
//
#include <hip/hip_runtime.h>
#include <cstdint>
#include <cstddef>

#define BDIM 256
#define NWG  256

constexpr int B_ = 64, S_ = 1024, I_ = 128, H_ = 512, O_ = 128;
constexpr size_t HB = (size_t)H_ * B_;   // 32768 floats per slab [k][b]

// ---- workspace (floats): slabs ~1.05MB, optional XT +33.5MB ----
constexpr size_t Y1_OFF  = 0;             // 2 slots (ring): y1[t] at slot t&1, seed y1[-1] at slot 1
constexpr size_t Y2_OFF  = Y1_OFF + 2 * HB;
constexpr size_t RH0_OFF = Y2_OFF + 2 * HB;
constexpr size_t RH1_OFF = RH0_OFF + HB;
constexpr size_t Z0_OFF  = RH1_OFF + HB;
constexpr size_t Z1_OFF  = Z0_OFF + HB;
constexpr size_t BAR_OFF = Z1_OFF + HB;   // 64 uints
constexpr size_t SLAB_TOT = BAR_OFF + 64;
constexpr size_t XT_OFF  = SLAB_TOT;      // [t][i][b] transposed input
constexpr size_t XT_FLOATS = (size_t)S_ * I_ * B_;
constexpr size_t WS_NEED_XT_BYTES = (XT_OFF + XT_FLOATS) * 4;

// ---------------- init: seed ring slot-1 with h0, zero barrier ----------------
__global__ void k_init(const float* __restrict__ hidden, float* __restrict__ ws) {
  int idx = blockIdx.x * 256 + threadIdx.x;           // 2*HB + 64 = 65600 items
  if (idx < (int)(2 * HB)) {
    int l = idx >> 15, r = idx & 32767;
    int k = r >> 6, b = r & 63;
    ws[(l ? Y2_OFF : Y1_OFF) + HB + r] = hidden[b * 1024 + l * 512 + k];
  } else if (idx < (int)(2 * HB) + 64) {
    ((unsigned int*)(ws + BAR_OFF))[idx - 2 * HB] = 0u;
  }
}

// ---------------- input transpose: XT[t][i][b] = input[b][t][i] ----------------
__global__ void k_transpose_x(const float* __restrict__ in, float* __restrict__ Xt) {
  const size_t NQ = (size_t)B_ * S_ * I_ / 4;
  for (size_t q = (size_t)blockIdx.x * blockDim.x + threadIdx.x; q < NQ;
       q += (size_t)gridDim.x * blockDim.x) {
    int i4 = (int)(q & 31);
    int t  = (int)((q >> 5) & 1023);
    int b  = (int)(q >> 15);
    float4 v = *(const float4*)(in + ((size_t)b * 1024 + t) * 128 + i4 * 4);
    float* dst = Xt + (size_t)t * 8192 + (size_t)(i4 * 4) * 64 + b;
    dst[0] = v.x; dst[64] = v.y; dst[128] = v.z; dst[192] = v.w;
  }
}

// ---------------- helpers ----------------
__device__ __forceinline__ void fmas(float4& a, float s, const float4 h) {
  a.x = fmaf(s, h.x, a.x); a.y = fmaf(s, h.y, a.y);
  a.z = fmaf(s, h.z, a.z); a.w = fmaf(s, h.w, a.w);
}

// C=8 dot region: src is [k][64] from region start; wAp points at wA[kbase*8]
__device__ __forceinline__ void dotA8(const float* __restrict__ src, const float* __restrict__ wAp,
                                      int nch, int kt, int b4, float4* acc) {
  #pragma unroll 4
  for (int ch = 0; ch < nch; ++ch) {
    int kk = ch * 16 + kt;
    float4 h = *(const float4*)(src + (size_t)kk * 64 + b4);
    const float* wp = wAp + kk * 8;
    float4 w0 = *(const float4*)wp;
    float4 w1 = *(const float4*)(wp + 4);
    fmas(acc[0], w0.x, h); fmas(acc[1], w0.y, h); fmas(acc[2], w0.z, h); fmas(acc[3], w0.w, h);
    fmas(acc[4], w1.x, h); fmas(acc[5], w1.y, h); fmas(acc[6], w1.z, h); fmas(acc[7], w1.w, h);
  }
}

// C=8, x directly from original [b][t][i] layout (fallback when ws too small for XT)
__device__ __forceinline__ void dotA8x(const float* __restrict__ xin, int tau,
                                       const float* __restrict__ wAp, int kt, int b4, float4* acc) {
  #pragma unroll 2
  for (int ch = 0; ch < 8; ++ch) {
    int i = ch * 16 + kt;
    float4 h;
    h.x = xin[(size_t)(b4 + 0) * 131072 + tau * 128 + i];
    h.y = xin[(size_t)(b4 + 1) * 131072 + tau * 128 + i];
    h.z = xin[(size_t)(b4 + 2) * 131072 + tau * 128 + i];
    h.w = xin[(size_t)(b4 + 3) * 131072 + tau * 128 + i];
    const float* wp = wAp + i * 8;
    float4 w0 = *(const float4*)wp;
    float4 w1 = *(const float4*)(wp + 4);
    fmas(acc[0], w0.x, h); fmas(acc[1], w0.y, h); fmas(acc[2], w0.z, h); fmas(acc[3], w0.w, h);
    fmas(acc[4], w1.x, h); fmas(acc[5], w1.y, h); fmas(acc[6], w1.z, h); fmas(acc[7], w1.w, h);
  }
}

// C=4 dot region
__device__ __forceinline__ void dotB4(const float* __restrict__ src, const float* __restrict__ wBp,
                                      int nch, int kt, int b4, float4* acc) {
  #pragma unroll 4
  for (int ch = 0; ch < nch; ++ch) {
    int kk = ch * 16 + kt;
    float4 h = *(const float4*)(src + (size_t)kk * 64 + b4);
    const float* wp = wBp + kk * 4;
    float4 w0 = *(const float4*)wp;
    fmas(acc[0], w0.x, h); fmas(acc[1], w0.y, h); fmas(acc[2], w0.z, h); fmas(acc[3], w0.w, h);
  }
}

__device__ __forceinline__ void dotB4x(const float* __restrict__ xin, int tau,
                                       const float* __restrict__ wBp, int kt, int b4, float4* acc) {
  #pragma unroll 2
  for (int ch = 0; ch < 8; ++ch) {
    int i = ch * 16 + kt;
    float4 h;
    h.x = xin[(size_t)(b4 + 0) * 131072 + tau * 128 + i];
    h.y = xin[(size_t)(b4 + 1) * 131072 + tau * 128 + i];
    h.z = xin[(size_t)(b4 + 2) * 131072 + tau * 128 + i];
    h.w = xin[(size_t)(b4 + 3) * 131072 + tau * 128 + i];
    const float* wp = wBp + i * 4;
    float4 w0 = *(const float4*)wp;
    fmas(acc[0], w0.x, h); fmas(acc[1], w0.y, h); fmas(acc[2], w0.z, h); fmas(acc[3], w0.w, h);
  }
}

__device__ __forceinline__ void grid_barrier(unsigned int* cnt, unsigned int* gen) {
  __threadfence();
  __syncthreads();
  if (threadIdx.x == 0) {
    unsigned int g = __hip_atomic_load(gen, __ATOMIC_RELAXED, __HIP_MEMORY_SCOPE_AGENT);
    unsigned int arr = __hip_atomic_fetch_add(cnt, 1u, __ATOMIC_ACQ_REL, __HIP_MEMORY_SCOPE_AGENT);
    if (arr == NWG - 1) {
      __hip_atomic_store(cnt, 0u, __ATOMIC_RELAXED, __HIP_MEMORY_SCOPE_AGENT);
      __hip_atomic_store(gen, g + 1u, __ATOMIC_RELEASE, __HIP_MEMORY_SCOPE_AGENT);
    } else {
      while (__hip_atomic_load(gen, __ATOMIC_RELAXED, __HIP_MEMORY_SCOPE_AGENT) == g) {
        __builtin_amdgcn_s_sleep(2);
      }
    }
  }
  __syncthreads();
  __threadfence();
}

// ---------------- persistent scan: weights LDS-resident across all stages ----------------
struct ScanArgs {
  float* ws;
  const float* xin;
  float* out;
  const float *Wzx0, *Wzh0, *bz0, *Wrx0, *Wrh0, *br0, *Wgx0, *Wgh0, *bg0;
  const float *Wzx1, *Wzh1, *bz1, *Wrx1, *Wrh1, *br1, *Wgx1, *Wgh1, *bg1;
  const float *Wout, *bout;
  int use_xt;
};

__launch_bounds__(BDIM, 1)
__global__ void k_scan(ScanArgs a) {
  float* ws = a.ws;
  unsigned int* bar = (unsigned int*)(ws + BAR_OFF);
  unsigned int* cnt = bar;
  unsigned int* gen = bar + 32;

  const int tid = threadIdx.x;
  const int wg  = blockIdx.x;
  const int kt  = tid >> 4;          // 0..15 (k-thread)
  const int bq  = tid & 15;          // 0..15 (batch quad)
  const int b4  = bq << 2;           // batch base (4 consecutive b)

  // phase A assignment: wg>>6 -> {L0z, L0r, L1z, L1r}, 8 cols each
  const int mA  = wg >> 6;
  const int lA  = mA >> 1;           // layer
  const int gA  = mA & 1;            // 0 z, 1 r
  const int jA0 = (wg & 63) * 8;
  const int KA  = (mA < 2) ? 640 : 1024;
  // phase B assignment: wg>>7 -> {L0g, L1g}, 4 cols each
  const int mB  = wg >> 7;
  const int jB0 = (wg & 127) * 4;
  const int KB  = mB ? 1024 : 640;

  // LDS: weights resident for the whole scan + reduction scratch
  __shared__ float wA[8192];         // [k][8] for this WG's A matrix (KA*8 used)
  __shared__ float wB[4096];         // [k][4] for this WG's g matrix (KB*4 used)
  __shared__ float wO[512];          // outproj column (wg<128)
  __shared__ float pA[9 * 64 * 17];  // partials: [c(9)][b(64)][kt(17 padded)]

  {  // one-time gather of this WG's weight columns (k-major source => short coalesced runs)
    const float* A0 = lA ? (gA ? a.Wrx1 : a.Wzx1) : (gA ? a.Wrh0 : a.Wzh0);
    const float* A1 = lA ? (gA ? a.Wrh1 : a.Wzh1) : (gA ? a.Wrx0 : a.Wzx0);
    for (int idx = tid; idx < KA * 8; idx += BDIM) {
      int k = idx >> 3, c = idx & 7;
      wA[idx] = (k < 512) ? A0[k * 512 + jA0 + c] : A1[(k - 512) * 512 + jA0 + c];
    }
    const float* B0 = mB ? a.Wgx1 : a.Wgh0;
    const float* B1 = mB ? a.Wgh1 : a.Wgx0;
    for (int idx = tid; idx < KB * 4; idx += BDIM) {
      int k = idx >> 2, c = idx & 3;
      wB[idx] = (k < 512) ? B0[k * 512 + jB0 + c] : B1[(k - 512) * 512 + jB0 + c];
    }
    if (wg < 128)
      for (int idx = tid; idx < 512; idx += BDIM) wO[idx] = a.Wout[(size_t)idx * 128 + wg];
  }
  // biases preloaded for reducer lanes
  const float* bAv = lA ? (gA ? a.br1 : a.bz1) : (gA ? a.br0 : a.bz0);
  const float biasA_0 = bAv[jA0 + (tid >> 6)];
  const float biasA_1 = bAv[jA0 + 4 + (tid >> 6)];
  const float biasB_0 = (mB ? a.bg1 : a.bg0)[jB0 + (tid >> 6)];
  const float boutW = (wg < 128) ? a.bout[wg] : 0.f;
  __syncthreads();

  const float* XT = ws + XT_OFF;

  for (int tau = 0; tau <= S_ + 1; ++tau) {
    const bool doL0 = (tau < S_);
    const bool doL1 = (tau >= 1) && (tau <= S_);
    const int slotP = (tau + 1) & 1;    // y1[tau-1] slot; y2[tau-1] write slot
    const int slotQ = tau & 1;          // y2[tau-2] slot; y1[tau] write slot
    const float* y1p = ws + Y1_OFF + (size_t)slotP * HB;   // y1[tau-1]: L0 h_prev, L1 x
    const float* y2p = ws + Y2_OFF + (size_t)slotQ * HB;   // y2[tau-2]: L1 h_prev, outproj src
    float* y1w = ws + Y1_OFF + (size_t)slotQ * HB;
    float* y2w = ws + Y2_OFF + (size_t)slotP * HB;

    // ================= phase A: z & r (+ fused outproj of t=tau-2) =================
    const bool actA = lA ? doL1 : doL0;
    float4 acc[8];
    #pragma unroll
    for (int c = 0; c < 8; ++c) acc[c] = make_float4(0.f, 0.f, 0.f, 0.f);
    if (actA) {
      dotA8(y1p, wA, 32, kt, b4, acc);                    // k in [0,512): y1[tau-1] for both layers
      if (mA < 2) {                                       // L0: x region, k in [512,640)
        if (a.use_xt) dotA8(XT + (size_t)tau * 8192, wA + 512 * 8, 8, kt, b4, acc);
        else          dotA8x(a.xin, tau, wA + 512 * 8, kt, b4, acc);
      } else {                                            // L1: h region, k in [512,1024)
        dotA8(y2p, wA + 512 * 8, 32, kt, b4, acc);
      }
    }
    const bool doOut = (tau >= 2) && (wg < 128);
    float4 accO = make_float4(0.f, 0.f, 0.f, 0.f);
    if (doOut) {
      #pragma unroll 4
      for (int ch = 0; ch < 32; ++ch) {
        int kk = ch * 16 + kt;
        float4 h = *(const float4*)(y2p + (size_t)kk * 64 + b4);
        fmas(accO, wO[kk], h);
      }
    }
    // partial store + reduce
    if (actA) {
      #pragma unroll
      for (int c = 0; c < 8; ++c) {
        float pv[4] = {acc[c].x, acc[c].y, acc[c].z, acc[c].w};
        #pragma unroll
        for (int j = 0; j < 4; ++j) pA[(c * 64 + b4 + j) * 17 + kt] = pv[j];
      }
    }
    if (doOut) {
      float pv[4] = {accO.x, accO.y, accO.z, accO.w};
      #pragma unroll
      for (int j = 0; j < 4; ++j) pA[(512 + b4 + j) * 17 + kt] = pv[j];
    }
    __syncthreads();
    if (actA) {
      #pragma unroll
      for (int r = 0; r < 2; ++r) {
        int idx = tid + (r << 8);
        int c = idx >> 6, b = idx & 63;
        float s = r ? biasA_1 : biasA_0;
        #pragma unroll
        for (int q = 0; q < 16; ++q) s += pA[(c * 64 + b) * 17 + q];
        float v = 1.0f / (1.0f + __expf(-s));
        size_t jb = (size_t)(jA0 + c) * 64 + b;
        if (gA == 0) {
          (ws + (lA ? Z1_OFF : Z0_OFF))[jb] = v;
        } else {
          const float* hpsl = lA ? y2p : y1p;
          (ws + (lA ? RH1_OFF : RH0_OFF))[jb] = v * hpsl[jb];
        }
      }
    }
    if (doOut && tid < 64) {
      float s = boutW;
      #pragma unroll
      for (int q = 0; q < 16; ++q) s += pA[(512 + tid) * 17 + q];
      a.out[((size_t)tid * 1024 + (tau - 2)) * 128 + wg] = s;
    }

    grid_barrier(cnt, gen);   // rh/z visible grid-wide

    // ================= phase B: g and h update =================
    const bool actB = mB ? doL1 : doL0;
    float4 accB[4];
    #pragma unroll
    for (int c = 0; c < 4; ++c) accB[c] = make_float4(0.f, 0.f, 0.f, 0.f);
    if (actB) {
      const float* r0 = mB ? y1p : (ws + RH0_OFF);        // k in [0,512)
      dotB4(r0, wB, 32, kt, b4, accB);
      if (mB) {
        dotB4(ws + RH1_OFF, wB + 512 * 4, 32, kt, b4, accB);
      } else {
        if (a.use_xt) dotB4(XT + (size_t)tau * 8192, wB + 512 * 4, 8, kt, b4, accB);
        else          dotB4x(a.xin, tau, wB + 512 * 4, kt, b4, accB);
      }
      #pragma unroll
      for (int c = 0; c < 4; ++c) {
        float pv[4] = {accB[c].x, accB[c].y, accB[c].z, accB[c].w};
        #pragma unroll
        for (int j = 0; j < 4; ++j) pA[(c * 64 + b4 + j) * 17 + kt] = pv[j];
      }
    }
    __syncthreads();
    if (actB) {
      int c = tid >> 6, b = tid & 63;
      float s = biasB_0;
      #pragma unroll
      for (int q = 0; q < 16; ++q) s += pA[(c * 64 + b) * 17 + q];
      float g = tanhf(s);
      size_t jb = (size_t)(jB0 + c) * 64 + b;
      float z  = (ws + (mB ? Z1_OFF : Z0_OFF))[jb];
      float hp = (mB ? y2p : y1p)[jb];
      float hn = fmaf(z, hp - g, g);                      // z*hp + (1-z)*g
      (mB ? y2w : y1w)[jb] = hn;
    }

    grid_barrier(cnt, gen);   // h slabs visible for next stage
  }
}

// ---------------- final hidden states: out[BSO + b*1024 + l*512 + j] ----------------
__global__ void k_hidden(const float* __restrict__ ws, float* __restrict__ out) {
  int idx = blockIdx.x * 256 + threadIdx.x;   // 65536
  int b = idx >> 10, rem = idx & 1023, l = rem >> 9, j = rem & 511;
  // y1[1023] at slot 1; y2[1023] written stage 1024 at slot (1024+1)&1 = 1
  const float* src = ws + (l ? Y2_OFF : Y1_OFF) + HB + (size_t)j * 64 + b;
  out[(size_t)B_ * S_ * O_ + idx] = *src;
}

// ---------------- launch ----------------
extern "C" void kernel_launch(void* const* d_in, const int* in_sizes, int n_in,
                              void* d_out, int out_size, void* d_ws, size_t ws_size,
                              hipStream_t stream) {
  const float* input  = (const float*)d_in[0];
  const float* hidden = (const float*)d_in[1];
  const float* Wzx0 = (const float*)d_in[2],  *Wzh0 = (const float*)d_in[3],  *bz0 = (const float*)d_in[4];
  const float* Wrx0 = (const float*)d_in[5],  *Wrh0 = (const float*)d_in[6],  *br0 = (const float*)d_in[7];
  const float* Wgx0 = (const float*)d_in[8],  *Wgh0 = (const float*)d_in[9],  *bg0 = (const float*)d_in[10];
  const float* Wzx1 = (const float*)d_in[11], *Wzh1 = (const float*)d_in[12], *bz1 = (const float*)d_in[13];
  const float* Wrx1 = (const float*)d_in[14], *Wrh1 = (const float*)d_in[15], *br1 = (const float*)d_in[16];
  const float* Wgx1 = (const float*)d_in[17], *Wgh1 = (const float*)d_in[18], *bg1 = (const float*)d_in[19];
  const float* Wout = (const float*)d_in[20], *bout = (const float*)d_in[21];
  float* ws = (float*)d_ws;
  float* out = (float*)d_out;

  const int use_xt = (ws_size >= WS_NEED_XT_BYTES) ? 1 : 0;

  k_init<<<257, BDIM, 0, stream>>>(hidden, ws);
  if (use_xt) k_transpose_x<<<2048, BDIM, 0, stream>>>(input, ws + XT_OFF);

  ScanArgs sa{ws, input, out,
              Wzx0, Wzh0, bz0, Wrx0, Wrh0, br0, Wgx0, Wgh0, bg0,
              Wzx1, Wzh1, bz1, Wrx1, Wrh1, br1, Wgx1, Wgh1, bg1,
              Wout, bout, use_xt};
  k_scan<<<dim3(NWG), dim3(BDIM), 0, stream>>>(sa);

  k_hidden<<<256, 256, 0, stream>>>(ws, out);
}

// Round 4
// 92430.396 us; speedup vs baseline: 1.4493x; 1.0937x over previous
//
#include <hip/hip_runtime.h>
#include <cstdint>
#include <cstddef>

#define BDIM 256
#define NWG  256

constexpr int B_ = 64, S_ = 1024, I_ = 128, H_ = 512, O_ = 128;
constexpr size_t HB = (size_t)H_ * B_;   // 32768 floats per slab [k][b]

// ---- workspace (floats): slabs ~1.06MB, optional XT +33.5MB ----
constexpr size_t Y1_OFF  = 0;             // 2 slots (ring): y1[t] at slot t&1, seed y1[-1] at slot 1
constexpr size_t Y2_OFF  = Y1_OFF + 2 * HB;
constexpr size_t RH0_OFF = Y2_OFF + 2 * HB;
constexpr size_t RH1_OFF = RH0_OFF + HB;
constexpr size_t Z0_OFF  = RH1_OFF + HB;
constexpr size_t Z1_OFF  = Z0_OFF + HB;
constexpr size_t BAR_OFF = Z1_OFF + HB;   // tree barrier: 34 lines x 64 uints = 2176 words
constexpr size_t BAR_WORDS = 34 * 64;
constexpr size_t SLAB_TOT = BAR_OFF + BAR_WORDS;
constexpr size_t XT_OFF  = SLAB_TOT;      // [t][i][b] transposed input
constexpr size_t XT_FLOATS = (size_t)S_ * I_ * B_;
constexpr size_t WS_NEED_XT_BYTES = (XT_OFF + XT_FLOATS) * 4;

// ---------------- init: seed ring slot-1 with h0, zero barrier ----------------
__global__ void k_init(const float* __restrict__ hidden, float* __restrict__ ws) {
  int idx = blockIdx.x * 256 + threadIdx.x;           // 2*HB + BAR_WORDS items
  if (idx < (int)(2 * HB)) {
    int l = idx >> 15, r = idx & 32767;
    int k = r >> 6, b = r & 63;
    ws[(l ? Y2_OFF : Y1_OFF) + HB + r] = hidden[b * 1024 + l * 512 + k];
  } else if (idx < (int)(2 * HB + BAR_WORDS)) {
    ((unsigned int*)(ws + BAR_OFF))[idx - 2 * HB] = 0u;
  }
}

// ---------------- input transpose: XT[t][i][b] = input[b][t][i] ----------------
__global__ void k_transpose_x(const float* __restrict__ in, float* __restrict__ Xt) {
  const size_t NQ = (size_t)B_ * S_ * I_ / 4;
  for (size_t q = (size_t)blockIdx.x * blockDim.x + threadIdx.x; q < NQ;
       q += (size_t)gridDim.x * blockDim.x) {
    int i4 = (int)(q & 31);
    int t  = (int)((q >> 5) & 1023);
    int b  = (int)(q >> 15);
    float4 v = *(const float4*)(in + ((size_t)b * 1024 + t) * 128 + i4 * 4);
    float* dst = Xt + (size_t)t * 8192 + (size_t)(i4 * 4) * 64 + b;
    dst[0] = v.x; dst[64] = v.y; dst[128] = v.z; dst[192] = v.w;
  }
}

// ---------------- helpers ----------------
__device__ __forceinline__ void fmas(float4& a, float s, const float4 h) {
  a.x = fmaf(s, h.x, a.x); a.y = fmaf(s, h.y, a.y);
  a.z = fmaf(s, h.z, a.z); a.w = fmaf(s, h.w, a.w);
}

// C=8 dot region: src is [k][64] from region start; wAp points at wA[kbase*8]
__device__ __forceinline__ void dotA8(const float* __restrict__ src, const float* __restrict__ wAp,
                                      int nch, int kt, int b4, float4* acc) {
  #pragma unroll 4
  for (int ch = 0; ch < nch; ++ch) {
    int kk = ch * 16 + kt;
    float4 h = *(const float4*)(src + (size_t)kk * 64 + b4);
    const float* wp = wAp + kk * 8;
    float4 w0 = *(const float4*)wp;
    float4 w1 = *(const float4*)(wp + 4);
    fmas(acc[0], w0.x, h); fmas(acc[1], w0.y, h); fmas(acc[2], w0.z, h); fmas(acc[3], w0.w, h);
    fmas(acc[4], w1.x, h); fmas(acc[5], w1.y, h); fmas(acc[6], w1.z, h); fmas(acc[7], w1.w, h);
  }
}

// C=8, x directly from original [b][t][i] layout (fallback when ws too small for XT)
__device__ __forceinline__ void dotA8x(const float* __restrict__ xin, int tau,
                                       const float* __restrict__ wAp, int kt, int b4, float4* acc) {
  #pragma unroll 2
  for (int ch = 0; ch < 8; ++ch) {
    int i = ch * 16 + kt;
    float4 h;
    h.x = xin[(size_t)(b4 + 0) * 131072 + tau * 128 + i];
    h.y = xin[(size_t)(b4 + 1) * 131072 + tau * 128 + i];
    h.z = xin[(size_t)(b4 + 2) * 131072 + tau * 128 + i];
    h.w = xin[(size_t)(b4 + 3) * 131072 + tau * 128 + i];
    const float* wp = wAp + i * 8;
    float4 w0 = *(const float4*)wp;
    float4 w1 = *(const float4*)(wp + 4);
    fmas(acc[0], w0.x, h); fmas(acc[1], w0.y, h); fmas(acc[2], w0.z, h); fmas(acc[3], w0.w, h);
    fmas(acc[4], w1.x, h); fmas(acc[5], w1.y, h); fmas(acc[6], w1.z, h); fmas(acc[7], w1.w, h);
  }
}

// C=4 dot region
__device__ __forceinline__ void dotB4(const float* __restrict__ src, const float* __restrict__ wBp,
                                      int nch, int kt, int b4, float4* acc) {
  #pragma unroll 4
  for (int ch = 0; ch < nch; ++ch) {
    int kk = ch * 16 + kt;
    float4 h = *(const float4*)(src + (size_t)kk * 64 + b4);
    const float* wp = wBp + kk * 4;
    float4 w0 = *(const float4*)wp;
    fmas(acc[0], w0.x, h); fmas(acc[1], w0.y, h); fmas(acc[2], w0.z, h); fmas(acc[3], w0.w, h);
  }
}

__device__ __forceinline__ void dotB4x(const float* __restrict__ xin, int tau,
                                       const float* __restrict__ wBp, int kt, int b4, float4* acc) {
  #pragma unroll 2
  for (int ch = 0; ch < 8; ++ch) {
    int i = ch * 16 + kt;
    float4 h;
    h.x = xin[(size_t)(b4 + 0) * 131072 + tau * 128 + i];
    h.y = xin[(size_t)(b4 + 1) * 131072 + tau * 128 + i];
    h.z = xin[(size_t)(b4 + 2) * 131072 + tau * 128 + i];
    h.w = xin[(size_t)(b4 + 3) * 131072 + tau * 128 + i];
    const float* wp = wBp + i * 4;
    float4 w0 = *(const float4*)wp;
    fmas(acc[0], w0.x, h); fmas(acc[1], w0.y, h); fmas(acc[2], w0.z, h); fmas(acc[3], w0.w, h);
  }
}

// ---- two-level tree barrier: 16 groups x 16 WGs, cumulative counters, spread lines ----
// layout (uint words): grp_cnt[g] @ g*64 | root_cnt @ 16*64 | grp_gen[g] @ (17+g)*64 | root_gen @ 33*64
__device__ __forceinline__ void grid_barrier(unsigned int* bar, unsigned int ph) {
  __threadfence();     // release: push my slab stores to the coherence point
  __syncthreads();
  if (threadIdx.x == 0) {
    const int g = (int)(blockIdx.x >> 4);
    unsigned int* grp_cnt  = bar + (size_t)g * 64;
    unsigned int* root_cnt = bar + 16 * 64;
    unsigned int* grp_gen  = bar + (size_t)(17 + g) * 64;
    unsigned int* root_gen = bar + 33 * 64;
    unsigned int r = __hip_atomic_fetch_add(grp_cnt, 1u, __ATOMIC_RELAXED, __HIP_MEMORY_SCOPE_AGENT);
    if (r == 16u * ph - 1u) {          // last of my group this phase
      unsigned int rr = __hip_atomic_fetch_add(root_cnt, 1u, __ATOMIC_RELAXED, __HIP_MEMORY_SCOPE_AGENT);
      if (rr == 16u * ph - 1u) {       // last group overall: release root
        __hip_atomic_store(root_gen, ph, __ATOMIC_RELAXED, __HIP_MEMORY_SCOPE_AGENT);
      } else {
        while (__hip_atomic_load(root_gen, __ATOMIC_RELAXED, __HIP_MEMORY_SCOPE_AGENT) < ph)
          __builtin_amdgcn_s_sleep(4);
      }
      __hip_atomic_store(grp_gen, ph, __ATOMIC_RELAXED, __HIP_MEMORY_SCOPE_AGENT);
    } else {
      while (__hip_atomic_load(grp_gen, __ATOMIC_RELAXED, __HIP_MEMORY_SCOPE_AGENT) < ph)
        __builtin_amdgcn_s_sleep(8);
    }
  }
  __syncthreads();
  __threadfence();     // acquire: invalidate stale L2/L1 before reading remote slabs
}

// ---------------- persistent scan: weights LDS-resident across all stages ----------------
struct ScanArgs {
  float* ws;
  const float* xin;
  float* out;
  const float *Wzx0, *Wzh0, *bz0, *Wrx0, *Wrh0, *br0, *Wgx0, *Wgh0, *bg0;
  const float *Wzx1, *Wzh1, *bz1, *Wrx1, *Wrh1, *br1, *Wgx1, *Wgh1, *bg1;
  const float *Wout, *bout;
  int use_xt;
};

__launch_bounds__(BDIM, 1)
__global__ void k_scan(ScanArgs a) {
  float* ws = a.ws;
  unsigned int* bar = (unsigned int*)(ws + BAR_OFF);

  const int tid = threadIdx.x;
  const int wg  = blockIdx.x;
  const int kt  = tid >> 4;          // 0..15 (k-thread)
  const int bq  = tid & 15;          // 0..15 (batch quad)
  const int b4  = bq << 2;           // batch base (4 consecutive b)

  // phase A assignment: wg>>6 -> {L0z, L0r, L1z, L1r}, 8 cols each
  const int mA  = wg >> 6;
  const int lA  = mA >> 1;           // layer
  const int gA  = mA & 1;            // 0 z, 1 r
  const int jA0 = (wg & 63) * 8;
  const int KA  = (mA < 2) ? 640 : 1024;
  // phase B assignment: wg>>7 -> {L0g, L1g}, 4 cols each
  const int mB  = wg >> 7;
  const int jB0 = (wg & 127) * 4;
  const int KB  = mB ? 1024 : 640;

  // LDS: weights resident for the whole scan + reduction scratch
  __shared__ float wA[8192];         // [k][8] for this WG's A matrix (KA*8 used)
  __shared__ float wB[4096];         // [k][4] for this WG's g matrix (KB*4 used)
  __shared__ float wO[512];          // outproj column (wg<128)
  __shared__ float pA[9 * 64 * 17];  // partials: [c(9)][b(64)][kt(17 padded)]

  {  // one-time gather of this WG's weight columns
    const float* A0 = lA ? (gA ? a.Wrx1 : a.Wzx1) : (gA ? a.Wrh0 : a.Wzh0);
    const float* A1 = lA ? (gA ? a.Wrh1 : a.Wzh1) : (gA ? a.Wrx0 : a.Wzx0);
    for (int idx = tid; idx < KA * 8; idx += BDIM) {
      int k = idx >> 3, c = idx & 7;
      wA[idx] = (k < 512) ? A0[k * 512 + jA0 + c] : A1[(k - 512) * 512 + jA0 + c];
    }
    const float* B0 = mB ? a.Wgx1 : a.Wgh0;
    const float* B1 = mB ? a.Wgh1 : a.Wgx0;
    for (int idx = tid; idx < KB * 4; idx += BDIM) {
      int k = idx >> 2, c = idx & 3;
      wB[idx] = (k < 512) ? B0[k * 512 + jB0 + c] : B1[(k - 512) * 512 + jB0 + c];
    }
    if (wg < 128)
      for (int idx = tid; idx < 512; idx += BDIM) wO[idx] = a.Wout[(size_t)idx * 128 + wg];
  }
  // biases preloaded for reducer lanes
  const float* bAv = lA ? (gA ? a.br1 : a.bz1) : (gA ? a.br0 : a.bz0);
  const float biasA_0 = bAv[jA0 + (tid >> 6)];
  const float biasA_1 = bAv[jA0 + 4 + (tid >> 6)];
  const float biasB_0 = (mB ? a.bg1 : a.bg0)[jB0 + (tid >> 6)];
  const float boutW = (wg < 128) ? a.bout[wg] : 0.f;
  __syncthreads();

  const float* XT = ws + XT_OFF;
  unsigned int ph = 1;

  for (int tau = 0; tau <= S_ + 1; ++tau) {
    const bool doL0 = (tau < S_);
    const bool doL1 = (tau >= 1) && (tau <= S_);
    const int slotP = (tau + 1) & 1;    // y1[tau-1] slot; y2[tau-1] write slot
    const int slotQ = tau & 1;          // y2[tau-2] slot; y1[tau] write slot
    const float* y1p = ws + Y1_OFF + (size_t)slotP * HB;   // y1[tau-1]: L0 h_prev, L1 x
    const float* y2p = ws + Y2_OFF + (size_t)slotQ * HB;   // y2[tau-2]: L1 h_prev, outproj src
    float* y1w = ws + Y1_OFF + (size_t)slotQ * HB;
    float* y2w = ws + Y2_OFF + (size_t)slotP * HB;

    // ================= phase A: z & r (+ fused outproj of t=tau-2) =================
    const bool actA = lA ? doL1 : doL0;
    float4 acc[8];
    #pragma unroll
    for (int c = 0; c < 8; ++c) acc[c] = make_float4(0.f, 0.f, 0.f, 0.f);
    if (actA) {
      dotA8(y1p, wA, 32, kt, b4, acc);                    // k in [0,512): y1[tau-1] for both layers
      if (mA < 2) {                                       // L0: x region, k in [512,640)
        if (a.use_xt) dotA8(XT + (size_t)tau * 8192, wA + 512 * 8, 8, kt, b4, acc);
        else          dotA8x(a.xin, tau, wA + 512 * 8, kt, b4, acc);
      } else {                                            // L1: h region, k in [512,1024)
        dotA8(y2p, wA + 512 * 8, 32, kt, b4, acc);
      }
    }
    const bool doOut = (tau >= 2) && (wg < 128);
    float4 accO = make_float4(0.f, 0.f, 0.f, 0.f);
    if (doOut) {
      #pragma unroll 4
      for (int ch = 0; ch < 32; ++ch) {
        int kk = ch * 16 + kt;
        float4 h = *(const float4*)(y2p + (size_t)kk * 64 + b4);
        fmas(accO, wO[kk], h);
      }
    }
    // partial store + reduce
    if (actA) {
      #pragma unroll
      for (int c = 0; c < 8; ++c) {
        float pv[4] = {acc[c].x, acc[c].y, acc[c].z, acc[c].w};
        #pragma unroll
        for (int j = 0; j < 4; ++j) pA[(c * 64 + b4 + j) * 17 + kt] = pv[j];
      }
    }
    if (doOut) {
      float pv[4] = {accO.x, accO.y, accO.z, accO.w};
      #pragma unroll
      for (int j = 0; j < 4; ++j) pA[(512 + b4 + j) * 17 + kt] = pv[j];
    }
    __syncthreads();
    if (actA) {
      #pragma unroll
      for (int r = 0; r < 2; ++r) {
        int idx = tid + (r << 8);
        int c = idx >> 6, b = idx & 63;
        float s = r ? biasA_1 : biasA_0;
        #pragma unroll
        for (int q = 0; q < 16; ++q) s += pA[(c * 64 + b) * 17 + q];
        float v = 1.0f / (1.0f + __expf(-s));
        size_t jb = (size_t)(jA0 + c) * 64 + b;
        if (gA == 0) {
          (ws + (lA ? Z1_OFF : Z0_OFF))[jb] = v;
        } else {
          const float* hpsl = lA ? y2p : y1p;
          (ws + (lA ? RH1_OFF : RH0_OFF))[jb] = v * hpsl[jb];
        }
      }
    }
    if (doOut && tid < 64) {
      float s = boutW;
      #pragma unroll
      for (int q = 0; q < 16; ++q) s += pA[(512 + tid) * 17 + q];
      a.out[((size_t)tid * 1024 + (tau - 2)) * 128 + wg] = s;
    }

    grid_barrier(bar, ph++);   // rh/z visible grid-wide

    // ================= phase B: g and h update =================
    const bool actB = mB ? doL1 : doL0;
    float4 accB[4];
    #pragma unroll
    for (int c = 0; c < 4; ++c) accB[c] = make_float4(0.f, 0.f, 0.f, 0.f);
    if (actB) {
      const float* r0 = mB ? y1p : (ws + RH0_OFF);        // k in [0,512)
      dotB4(r0, wB, 32, kt, b4, accB);
      if (mB) {
        dotB4(ws + RH1_OFF, wB + 512 * 4, 32, kt, b4, accB);
      } else {
        if (a.use_xt) dotB4(XT + (size_t)tau * 8192, wB + 512 * 4, 8, kt, b4, accB);
        else          dotB4x(a.xin, tau, wB + 512 * 4, kt, b4, accB);
      }
      #pragma unroll
      for (int c = 0; c < 4; ++c) {
        float pv[4] = {accB[c].x, accB[c].y, accB[c].z, accB[c].w};
        #pragma unroll
        for (int j = 0; j < 4; ++j) pA[(c * 64 + b4 + j) * 17 + kt] = pv[j];
      }
    }
    __syncthreads();
    if (actB) {
      int c = tid >> 6, b = tid & 63;
      float s = biasB_0;
      #pragma unroll
      for (int q = 0; q < 16; ++q) s += pA[(c * 64 + b) * 17 + q];
      float g = tanhf(s);
      size_t jb = (size_t)(jB0 + c) * 64 + b;
      float z  = (ws + (mB ? Z1_OFF : Z0_OFF))[jb];
      float hp = (mB ? y2p : y1p)[jb];
      float hn = fmaf(z, hp - g, g);                      // z*hp + (1-z)*g
      (mB ? y2w : y1w)[jb] = hn;
    }

    grid_barrier(bar, ph++);   // h slabs visible for next stage
  }
}

// ---------------- final hidden states: out[BSO + b*1024 + l*512 + j] ----------------
__global__ void k_hidden(const float* __restrict__ ws, float* __restrict__ out) {
  int idx = blockIdx.x * 256 + threadIdx.x;   // 65536
  int b = idx >> 10, rem = idx & 1023, l = rem >> 9, j = rem & 511;
  // y1[1023] at slot 1; y2[1023] written stage 1024 at slot (1024+1)&1 = 1
  const float* src = ws + (l ? Y2_OFF : Y1_OFF) + HB + (size_t)j * 64 + b;
  out[(size_t)B_ * S_ * O_ + idx] = *src;
}

// ---------------- launch ----------------
extern "C" void kernel_launch(void* const* d_in, const int* in_sizes, int n_in,
                              void* d_out, int out_size, void* d_ws, size_t ws_size,
                              hipStream_t stream) {
  const float* input  = (const float*)d_in[0];
  const float* hidden = (const float*)d_in[1];
  const float* Wzx0 = (const float*)d_in[2],  *Wzh0 = (const float*)d_in[3],  *bz0 = (const float*)d_in[4];
  const float* Wrx0 = (const float*)d_in[5],  *Wrh0 = (const float*)d_in[6],  *br0 = (const float*)d_in[7];
  const float* Wgx0 = (const float*)d_in[8],  *Wgh0 = (const float*)d_in[9],  *bg0 = (const float*)d_in[10];
  const float* Wzx1 = (const float*)d_in[11], *Wzh1 = (const float*)d_in[12], *bz1 = (const float*)d_in[13];
  const float* Wrx1 = (const float*)d_in[14], *Wrh1 = (const float*)d_in[15], *br1 = (const float*)d_in[16];
  const float* Wgx1 = (const float*)d_in[17], *Wgh1 = (const float*)d_in[18], *bg1 = (const float*)d_in[19];
  const float* Wout = (const float*)d_in[20], *bout = (const float*)d_in[21];
  float* ws = (float*)d_ws;
  float* out = (float*)d_out;

  const int use_xt = (ws_size >= WS_NEED_XT_BYTES) ? 1 : 0;

  k_init<<<265, BDIM, 0, stream>>>(hidden, ws);
  if (use_xt) k_transpose_x<<<2048, BDIM, 0, stream>>>(input, ws + XT_OFF);

  ScanArgs sa{ws, input, out,
              Wzx0, Wzh0, bz0, Wrx0, Wrh0, br0, Wgx0, Wgh0, bg0,
              Wzx1, Wzh1, bz1, Wrx1, Wrh1, br1, Wgx1, Wgh1, bg1,
              Wout, bout, use_xt};
  k_scan<<<dim3(NWG), dim3(BDIM), 0, stream>>>(sa);

  k_hidden<<<256, 256, 0, stream>>>(ws, out);
}

// Round 5
// 16745.909 us; speedup vs baseline: 7.9996x; 5.5196x over previous
//
#include <hip/hip_runtime.h>
#include <cstdint>
#include <cstddef>

#define BDIM 256
#define NWG  256

constexpr int B_ = 64, S_ = 1024, I_ = 128, H_ = 512, O_ = 128;
constexpr size_t HB = (size_t)H_ * B_;   // 32768 floats per slab [k][b]

// ---- workspace (floats): slabs ~1.06MB, optional XT +33.5MB ----
constexpr size_t Y1_OFF  = 0;             // 2 slots (ring): y1[t] at slot t&1, seed y1[-1] at slot 1
constexpr size_t Y2_OFF  = Y1_OFF + 2 * HB;
constexpr size_t RH0_OFF = Y2_OFF + 2 * HB;
constexpr size_t RH1_OFF = RH0_OFF + HB;
constexpr size_t Z0_OFF  = RH1_OFF + HB;
constexpr size_t Z1_OFF  = Z0_OFF + HB;
constexpr size_t BAR_OFF = Z1_OFF + HB;   // tree barrier: 34 lines x 64 uints
constexpr size_t BAR_WORDS = 34 * 64;
constexpr size_t SLAB_TOT = BAR_OFF + BAR_WORDS;
constexpr size_t XT_OFF  = SLAB_TOT;      // [t][i][b] transposed input (immutable during scan)
constexpr size_t XT_FLOATS = (size_t)S_ * I_ * B_;
constexpr size_t WS_NEED_XT_BYTES = (XT_OFF + XT_FLOATS) * 4;

// ---------------- LLC (agent-scope, L2-bypassing) access helpers ----------------
// Relaxed agent atomics lower to sc0/sc1 global accesses that operate at the LLC,
// giving cross-XCD coherence with ZERO buffer_wbl2/buffer_inv cache maintenance.
__device__ __forceinline__ float4 llc_load4(const float* p) {
  const unsigned long long* q = (const unsigned long long*)p;
  unsigned long long lo = __hip_atomic_load(q,     __ATOMIC_RELAXED, __HIP_MEMORY_SCOPE_AGENT);
  unsigned long long hi = __hip_atomic_load(q + 1, __ATOMIC_RELAXED, __HIP_MEMORY_SCOPE_AGENT);
  union { unsigned long long u[2]; float4 v; } c;
  c.u[0] = lo; c.u[1] = hi;
  return c.v;
}
__device__ __forceinline__ float llc_loadf(const float* p) {
  unsigned int u = __hip_atomic_load((const unsigned int*)p, __ATOMIC_RELAXED,
                                     __HIP_MEMORY_SCOPE_AGENT);
  union { unsigned int u; float f; } c; c.u = u;
  return c.f;
}
__device__ __forceinline__ void llc_storef(float* p, float x) {
  union { float f; unsigned int u; } c; c.f = x;
  __hip_atomic_store((unsigned int*)p, c.u, __ATOMIC_RELAXED, __HIP_MEMORY_SCOPE_AGENT);
}

// ---------------- init: seed ring slot-1 with h0, zero barrier ----------------
__global__ void k_init(const float* __restrict__ hidden, float* __restrict__ ws) {
  int idx = blockIdx.x * 256 + threadIdx.x;           // 2*HB + BAR_WORDS items
  if (idx < (int)(2 * HB)) {
    int l = idx >> 15, r = idx & 32767;
    int k = r >> 6, b = r & 63;
    ws[(l ? Y2_OFF : Y1_OFF) + HB + r] = hidden[b * 1024 + l * 512 + k];
  } else if (idx < (int)(2 * HB + BAR_WORDS)) {
    ((unsigned int*)(ws + BAR_OFF))[idx - 2 * HB] = 0u;
  }
}

// ---------------- input transpose: XT[t][i][b] = input[b][t][i] ----------------
__global__ void k_transpose_x(const float* __restrict__ in, float* __restrict__ Xt) {
  const size_t NQ = (size_t)B_ * S_ * I_ / 4;
  for (size_t q = (size_t)blockIdx.x * blockDim.x + threadIdx.x; q < NQ;
       q += (size_t)gridDim.x * blockDim.x) {
    int i4 = (int)(q & 31);
    int t  = (int)((q >> 5) & 1023);
    int b  = (int)(q >> 15);
    float4 v = *(const float4*)(in + ((size_t)b * 1024 + t) * 128 + i4 * 4);
    float* dst = Xt + (size_t)t * 8192 + (size_t)(i4 * 4) * 64 + b;
    dst[0] = v.x; dst[64] = v.y; dst[128] = v.z; dst[192] = v.w;
  }
}

// ---------------- dot helpers ----------------
__device__ __forceinline__ void fmas(float4& a, float s, const float4 h) {
  a.x = fmaf(s, h.x, a.x); a.y = fmaf(s, h.y, a.y);
  a.z = fmaf(s, h.z, a.z); a.w = fmaf(s, h.w, a.w);
}

// C=8 dot over a mutable slab region (LLC loads)
__device__ __forceinline__ void dotA8(const float* __restrict__ src, const float* __restrict__ wAp,
                                      int nch, int kt, int b4, float4* acc) {
  #pragma unroll 8
  for (int ch = 0; ch < nch; ++ch) {
    int kk = ch * 16 + kt;
    float4 h = llc_load4(src + (size_t)kk * 64 + b4);
    const float* wp = wAp + kk * 8;
    float4 w0 = *(const float4*)wp;
    float4 w1 = *(const float4*)(wp + 4);
    fmas(acc[0], w0.x, h); fmas(acc[1], w0.y, h); fmas(acc[2], w0.z, h); fmas(acc[3], w0.w, h);
    fmas(acc[4], w1.x, h); fmas(acc[5], w1.y, h); fmas(acc[6], w1.z, h); fmas(acc[7], w1.w, h);
  }
}

// C=8 dot over an immutable region (normal cached loads; XT)
__device__ __forceinline__ void dotA8c(const float* __restrict__ src, const float* __restrict__ wAp,
                                       int nch, int kt, int b4, float4* acc) {
  #pragma unroll 8
  for (int ch = 0; ch < nch; ++ch) {
    int kk = ch * 16 + kt;
    float4 h = *(const float4*)(src + (size_t)kk * 64 + b4);
    const float* wp = wAp + kk * 8;
    float4 w0 = *(const float4*)wp;
    float4 w1 = *(const float4*)(wp + 4);
    fmas(acc[0], w0.x, h); fmas(acc[1], w0.y, h); fmas(acc[2], w0.z, h); fmas(acc[3], w0.w, h);
    fmas(acc[4], w1.x, h); fmas(acc[5], w1.y, h); fmas(acc[6], w1.z, h); fmas(acc[7], w1.w, h);
  }
}

// C=8, x directly from original [b][t][i] layout (fallback; immutable)
__device__ __forceinline__ void dotA8x(const float* __restrict__ xin, int tau,
                                       const float* __restrict__ wAp, int kt, int b4, float4* acc) {
  #pragma unroll 2
  for (int ch = 0; ch < 8; ++ch) {
    int i = ch * 16 + kt;
    float4 h;
    h.x = xin[(size_t)(b4 + 0) * 131072 + tau * 128 + i];
    h.y = xin[(size_t)(b4 + 1) * 131072 + tau * 128 + i];
    h.z = xin[(size_t)(b4 + 2) * 131072 + tau * 128 + i];
    h.w = xin[(size_t)(b4 + 3) * 131072 + tau * 128 + i];
    const float* wp = wAp + i * 8;
    float4 w0 = *(const float4*)wp;
    float4 w1 = *(const float4*)(wp + 4);
    fmas(acc[0], w0.x, h); fmas(acc[1], w0.y, h); fmas(acc[2], w0.z, h); fmas(acc[3], w0.w, h);
    fmas(acc[4], w1.x, h); fmas(acc[5], w1.y, h); fmas(acc[6], w1.z, h); fmas(acc[7], w1.w, h);
  }
}

// C=4 dot over a mutable slab region (LLC loads)
__device__ __forceinline__ void dotB4(const float* __restrict__ src, const float* __restrict__ wBp,
                                      int nch, int kt, int b4, float4* acc) {
  #pragma unroll 8
  for (int ch = 0; ch < nch; ++ch) {
    int kk = ch * 16 + kt;
    float4 h = llc_load4(src + (size_t)kk * 64 + b4);
    const float* wp = wBp + kk * 4;
    float4 w0 = *(const float4*)wp;
    fmas(acc[0], w0.x, h); fmas(acc[1], w0.y, h); fmas(acc[2], w0.z, h); fmas(acc[3], w0.w, h);
  }
}

// C=4 dot over an immutable region (XT)
__device__ __forceinline__ void dotB4c(const float* __restrict__ src, const float* __restrict__ wBp,
                                       int nch, int kt, int b4, float4* acc) {
  #pragma unroll 8
  for (int ch = 0; ch < nch; ++ch) {
    int kk = ch * 16 + kt;
    float4 h = *(const float4*)(src + (size_t)kk * 64 + b4);
    const float* wp = wBp + kk * 4;
    float4 w0 = *(const float4*)wp;
    fmas(acc[0], w0.x, h); fmas(acc[1], w0.y, h); fmas(acc[2], w0.z, h); fmas(acc[3], w0.w, h);
  }
}

__device__ __forceinline__ void dotB4x(const float* __restrict__ xin, int tau,
                                       const float* __restrict__ wBp, int kt, int b4, float4* acc) {
  #pragma unroll 2
  for (int ch = 0; ch < 8; ++ch) {
    int i = ch * 16 + kt;
    float4 h;
    h.x = xin[(size_t)(b4 + 0) * 131072 + tau * 128 + i];
    h.y = xin[(size_t)(b4 + 1) * 131072 + tau * 128 + i];
    h.z = xin[(size_t)(b4 + 2) * 131072 + tau * 128 + i];
    h.w = xin[(size_t)(b4 + 3) * 131072 + tau * 128 + i];
    const float* wp = wBp + i * 4;
    float4 w0 = *(const float4*)wp;
    fmas(acc[0], w0.x, h); fmas(acc[1], w0.y, h); fmas(acc[2], w0.z, h); fmas(acc[3], w0.w, h);
  }
}

// ---- fence-free two-level tree barrier: 16 groups x 16 WGs, cumulative counters ----
// Safe because ALL mutable cross-WG data moves via agent-scope (LLC) atomics: no stale
// L2 copies can exist, so no acquire-invalidate or release-writeback is needed.
// __syncthreads() drains vmcnt(0) (compiler-inserted), so every wave's LLC stores are
// complete before lane 0 arrives.
__device__ __forceinline__ void grid_barrier(unsigned int* bar, unsigned int ph) {
  __syncthreads();
  asm volatile("" ::: "memory");
  if (threadIdx.x == 0) {
    const int g = (int)(blockIdx.x >> 4);
    unsigned int* grp_cnt  = bar + (size_t)g * 64;
    unsigned int* root_cnt = bar + 16 * 64;
    unsigned int* grp_gen  = bar + (size_t)(17 + g) * 64;
    unsigned int* root_gen = bar + 33 * 64;
    unsigned int r = __hip_atomic_fetch_add(grp_cnt, 1u, __ATOMIC_RELAXED, __HIP_MEMORY_SCOPE_AGENT);
    if (r == 16u * ph - 1u) {          // last of my group this phase
      unsigned int rr = __hip_atomic_fetch_add(root_cnt, 1u, __ATOMIC_RELAXED, __HIP_MEMORY_SCOPE_AGENT);
      if (rr == 16u * ph - 1u) {       // last group overall: release root
        __hip_atomic_store(root_gen, ph, __ATOMIC_RELAXED, __HIP_MEMORY_SCOPE_AGENT);
      } else {
        while (__hip_atomic_load(root_gen, __ATOMIC_RELAXED, __HIP_MEMORY_SCOPE_AGENT) < ph)
          __builtin_amdgcn_s_sleep(1);
      }
      __hip_atomic_store(grp_gen, ph, __ATOMIC_RELAXED, __HIP_MEMORY_SCOPE_AGENT);
    } else {
      while (__hip_atomic_load(grp_gen, __ATOMIC_RELAXED, __HIP_MEMORY_SCOPE_AGENT) < ph)
        __builtin_amdgcn_s_sleep(1);
    }
  }
  asm volatile("" ::: "memory");
  __syncthreads();
}

// ---------------- persistent scan: weights LDS-resident across all stages ----------------
struct ScanArgs {
  float* ws;
  const float* xin;
  float* out;
  const float *Wzx0, *Wzh0, *bz0, *Wrx0, *Wrh0, *br0, *Wgx0, *Wgh0, *bg0;
  const float *Wzx1, *Wzh1, *bz1, *Wrx1, *Wrh1, *br1, *Wgx1, *Wgh1, *bg1;
  const float *Wout, *bout;
  int use_xt;
};

__launch_bounds__(BDIM, 1)
__global__ void k_scan(ScanArgs a) {
  float* ws = a.ws;
  unsigned int* bar = (unsigned int*)(ws + BAR_OFF);

  const int tid = threadIdx.x;
  const int wg  = blockIdx.x;
  const int kt  = tid >> 4;          // 0..15 (k-thread)
  const int bq  = tid & 15;          // 0..15 (batch quad)
  const int b4  = bq << 2;           // batch base (4 consecutive b)

  // phase A assignment: wg>>6 -> {L0z, L0r, L1z, L1r}, 8 cols each
  const int mA  = wg >> 6;
  const int lA  = mA >> 1;           // layer
  const int gA  = mA & 1;            // 0 z, 1 r
  const int jA0 = (wg & 63) * 8;
  const int KA  = (mA < 2) ? 640 : 1024;
  // phase B assignment: wg>>7 -> {L0g, L1g}, 4 cols each
  const int mB  = wg >> 7;
  const int jB0 = (wg & 127) * 4;
  const int KB  = mB ? 1024 : 640;

  // LDS: weights resident for the whole scan + reduction scratch
  __shared__ float wA[8192];         // [k][8] for this WG's A matrix (KA*8 used)
  __shared__ float wB[4096];         // [k][4] for this WG's g matrix (KB*4 used)
  __shared__ float wO[512];          // outproj column (wg<128)
  __shared__ float pA[9 * 64 * 17];  // partials: [c(9)][b(64)][kt(17 padded)]

  {  // one-time gather of this WG's weight columns (cached loads; immutable)
    const float* A0 = lA ? (gA ? a.Wrx1 : a.Wzx1) : (gA ? a.Wrh0 : a.Wzh0);
    const float* A1 = lA ? (gA ? a.Wrh1 : a.Wzh1) : (gA ? a.Wrx0 : a.Wzx0);
    for (int idx = tid; idx < KA * 8; idx += BDIM) {
      int k = idx >> 3, c = idx & 7;
      wA[idx] = (k < 512) ? A0[k * 512 + jA0 + c] : A1[(k - 512) * 512 + jA0 + c];
    }
    const float* B0 = mB ? a.Wgx1 : a.Wgh0;
    const float* B1 = mB ? a.Wgh1 : a.Wgx0;
    for (int idx = tid; idx < KB * 4; idx += BDIM) {
      int k = idx >> 2, c = idx & 3;
      wB[idx] = (k < 512) ? B0[k * 512 + jB0 + c] : B1[(k - 512) * 512 + jB0 + c];
    }
    if (wg < 128)
      for (int idx = tid; idx < 512; idx += BDIM) wO[idx] = a.Wout[(size_t)idx * 128 + wg];
  }
  // biases preloaded for reducer lanes
  const float* bAv = lA ? (gA ? a.br1 : a.bz1) : (gA ? a.br0 : a.bz0);
  const float biasA_0 = bAv[jA0 + (tid >> 6)];
  const float biasA_1 = bAv[jA0 + 4 + (tid >> 6)];
  const float biasB_0 = (mB ? a.bg1 : a.bg0)[jB0 + (tid >> 6)];
  const float boutW = (wg < 128) ? a.bout[wg] : 0.f;
  __syncthreads();

  const float* XT = ws + XT_OFF;
  unsigned int ph = 1;

  for (int tau = 0; tau <= S_ + 1; ++tau) {
    const bool doL0 = (tau < S_);
    const bool doL1 = (tau >= 1) && (tau <= S_);
    const int slotP = (tau + 1) & 1;    // y1[tau-1] slot; y2[tau-1] write slot
    const int slotQ = tau & 1;          // y2[tau-2] slot; y1[tau] write slot
    const float* y1p = ws + Y1_OFF + (size_t)slotP * HB;   // y1[tau-1]: L0 h_prev, L1 x
    const float* y2p = ws + Y2_OFF + (size_t)slotQ * HB;   // y2[tau-2]: L1 h_prev, outproj src
    float* y1w = ws + Y1_OFF + (size_t)slotQ * HB;
    float* y2w = ws + Y2_OFF + (size_t)slotP * HB;

    // ================= phase A: z & r (+ fused outproj of t=tau-2) =================
    const bool actA = lA ? doL1 : doL0;
    float4 acc[8];
    #pragma unroll
    for (int c = 0; c < 8; ++c) acc[c] = make_float4(0.f, 0.f, 0.f, 0.f);
    if (actA) {
      dotA8(y1p, wA, 32, kt, b4, acc);                    // k in [0,512): y1[tau-1] both layers
      if (mA < 2) {                                       // L0: x region, k in [512,640)
        if (a.use_xt) dotA8c(XT + (size_t)tau * 8192, wA + 512 * 8, 8, kt, b4, acc);
        else          dotA8x(a.xin, tau, wA + 512 * 8, kt, b4, acc);
      } else {                                            // L1: h region, k in [512,1024)
        dotA8(y2p, wA + 512 * 8, 32, kt, b4, acc);
      }
    }
    const bool doOut = (tau >= 2) && (wg < 128);
    float4 accO = make_float4(0.f, 0.f, 0.f, 0.f);
    if (doOut) {
      #pragma unroll 8
      for (int ch = 0; ch < 32; ++ch) {
        int kk = ch * 16 + kt;
        float4 h = llc_load4(y2p + (size_t)kk * 64 + b4);
        fmas(accO, wO[kk], h);
      }
    }
    // partial store + reduce
    if (actA) {
      #pragma unroll
      for (int c = 0; c < 8; ++c) {
        float pv[4] = {acc[c].x, acc[c].y, acc[c].z, acc[c].w};
        #pragma unroll
        for (int j = 0; j < 4; ++j) pA[(c * 64 + b4 + j) * 17 + kt] = pv[j];
      }
    }
    if (doOut) {
      float pv[4] = {accO.x, accO.y, accO.z, accO.w};
      #pragma unroll
      for (int j = 0; j < 4; ++j) pA[(512 + b4 + j) * 17 + kt] = pv[j];
    }
    __syncthreads();
    if (actA) {
      #pragma unroll
      for (int r = 0; r < 2; ++r) {
        int idx = tid + (r << 8);
        int c = idx >> 6, b = idx & 63;
        float s = r ? biasA_1 : biasA_0;
        #pragma unroll
        for (int q = 0; q < 16; ++q) s += pA[(c * 64 + b) * 17 + q];
        float v = 1.0f / (1.0f + __expf(-s));
        size_t jb = (size_t)(jA0 + c) * 64 + b;
        if (gA == 0) {
          llc_storef(ws + (lA ? Z1_OFF : Z0_OFF) + jb, v);
        } else {
          const float* hpsl = lA ? y2p : y1p;
          float hp = llc_loadf(hpsl + jb);
          llc_storef(ws + (lA ? RH1_OFF : RH0_OFF) + jb, v * hp);
        }
      }
    }
    if (doOut && tid < 64) {
      float s = boutW;
      #pragma unroll
      for (int q = 0; q < 16; ++q) s += pA[(512 + tid) * 17 + q];
      a.out[((size_t)tid * 1024 + (tau - 2)) * 128 + wg] = s;
    }

    grid_barrier(bar, ph++);   // rh/z visible grid-wide

    // ================= phase B: g and h update =================
    const bool actB = mB ? doL1 : doL0;
    float4 accB[4];
    #pragma unroll
    for (int c = 0; c < 4; ++c) accB[c] = make_float4(0.f, 0.f, 0.f, 0.f);
    if (actB) {
      const float* r0 = mB ? y1p : (ws + RH0_OFF);        // k in [0,512)
      dotB4(r0, wB, 32, kt, b4, accB);
      if (mB) {
        dotB4(ws + RH1_OFF, wB + 512 * 4, 32, kt, b4, accB);
      } else {
        if (a.use_xt) dotB4c(XT + (size_t)tau * 8192, wB + 512 * 4, 8, kt, b4, accB);
        else          dotB4x(a.xin, tau, wB + 512 * 4, kt, b4, accB);
      }
      #pragma unroll
      for (int c = 0; c < 4; ++c) {
        float pv[4] = {accB[c].x, accB[c].y, accB[c].z, accB[c].w};
        #pragma unroll
        for (int j = 0; j < 4; ++j) pA[(c * 64 + b4 + j) * 17 + kt] = pv[j];
      }
    }
    __syncthreads();
    if (actB) {
      int c = tid >> 6, b = tid & 63;
      float s = biasB_0;
      #pragma unroll
      for (int q = 0; q < 16; ++q) s += pA[(c * 64 + b) * 17 + q];
      float g = tanhf(s);
      size_t jb = (size_t)(jB0 + c) * 64 + b;
      float z  = llc_loadf(ws + (mB ? Z1_OFF : Z0_OFF) + jb);
      float hp = llc_loadf((mB ? y2p : y1p) + jb);
      float hn = fmaf(z, hp - g, g);                      // z*hp + (1-z)*g
      llc_storef((mB ? y2w : y1w) + jb, hn);
    }

    grid_barrier(bar, ph++);   // h slabs visible for next stage
  }
}

// ---------------- final hidden states: out[BSO + b*1024 + l*512 + j] ----------------
__global__ void k_hidden(const float* __restrict__ ws, float* __restrict__ out) {
  int idx = blockIdx.x * 256 + threadIdx.x;   // 65536
  int b = idx >> 10, rem = idx & 1023, l = rem >> 9, j = rem & 511;
  // y1[1023] at slot 1; y2[1023] written stage 1024 at slot (1024+1)&1 = 1
  const float* src = ws + (l ? Y2_OFF : Y1_OFF) + HB + (size_t)j * 64 + b;
  out[(size_t)B_ * S_ * O_ + idx] = *src;
}

// ---------------- launch ----------------
extern "C" void kernel_launch(void* const* d_in, const int* in_sizes, int n_in,
                              void* d_out, int out_size, void* d_ws, size_t ws_size,
                              hipStream_t stream) {
  const float* input  = (const float*)d_in[0];
  const float* hidden = (const float*)d_in[1];
  const float* Wzx0 = (const float*)d_in[2],  *Wzh0 = (const float*)d_in[3],  *bz0 = (const float*)d_in[4];
  const float* Wrx0 = (const float*)d_in[5],  *Wrh0 = (const float*)d_in[6],  *br0 = (const float*)d_in[7];
  const float* Wgx0 = (const float*)d_in[8],  *Wgh0 = (const float*)d_in[9],  *bg0 = (const float*)d_in[10];
  const float* Wzx1 = (const float*)d_in[11], *Wzh1 = (const float*)d_in[12], *bz1 = (const float*)d_in[13];
  const float* Wrx1 = (const float*)d_in[14], *Wrh1 = (const float*)d_in[15], *br1 = (const float*)d_in[16];
  const float* Wgx1 = (const float*)d_in[17], *Wgh1 = (const float*)d_in[18], *bg1 = (const float*)d_in[19];
  const float* Wout = (const float*)d_in[20], *bout = (const float*)d_in[21];
  float* ws = (float*)d_ws;
  float* out = (float*)d_out;

  const int use_xt = (ws_size >= WS_NEED_XT_BYTES) ? 1 : 0;

  k_init<<<265, BDIM, 0, stream>>>(hidden, ws);
  if (use_xt) k_transpose_x<<<2048, BDIM, 0, stream>>>(input, ws + XT_OFF);

  ScanArgs sa{ws, input, out,
              Wzx0, Wzh0, bz0, Wrx0, Wrh0, br0, Wgx0, Wgh0, bg0,
              Wzx1, Wzh1, bz1, Wrx1, Wrh1, br1, Wgx1, Wgh1, bg1,
              Wout, bout, use_xt};
  k_scan<<<dim3(NWG), dim3(BDIM), 0, stream>>>(sa);

  k_hidden<<<256, 256, 0, stream>>>(ws, out);
}